// Round 14
// baseline (165.262 us; speedup 1.0000x reference)
//
#include <hip/hip_runtime.h>
#include <stdint.h>

#define BATCH 2048
#define INF 1024
#define OUTF 1024
#define GRID_G 8
#define KTOT 9216   // INF + INF*GRID_G (Wcat layout)

#define SK 8
#define MTT 8            // BATCH/256
#define NTT 4            // OUTF/256
#define CSLAB ((size_t)BATCH * OUTF)

typedef __attribute__((ext_vector_type(8))) short short8_t;
typedef __attribute__((ext_vector_type(4))) float f32x4_t;
typedef __attribute__((ext_vector_type(8))) unsigned short u16x8_t;

__device__ __forceinline__ unsigned short f2bf(float f) {
  unsigned int u = __float_as_uint(f);
  u += 0x7FFFu + ((u >> 16) & 1u);
  return (unsigned short)(u >> 16);
}

__device__ __forceinline__ float bf2f(unsigned short h) {
  return __uint_as_float((unsigned int)h << 16);
}

__device__ __forceinline__ void async16(void* lds, const void* g) {
  __builtin_amdgcn_global_load_lds(
      (const __attribute__((address_space(1))) void*)g,
      (__attribute__((address_space(3))) void*)lds, 16, 0, 0);
}

// frag[j] = (j==idx) ? w : 0 over 8 bf16, from packed (bf16 w | idx<<16)
__device__ __forceinline__ short8_t onehot_frag(unsigned int p) {
  unsigned int wlo = p & 0xFFFFu;
  unsigned int idx = p >> 16;
  unsigned int sel = (idx & 1u) ? (wlo << 16) : wlo;
  unsigned int jt = idx >> 1;
  union { unsigned int u[4]; short8_t s; } r;
  r.u[0] = (jt == 0u) ? sel : 0u;
  r.u[1] = (jt == 1u) ? sel : 0u;
  r.u[2] = (jt == 2u) ? sel : 0u;
  r.u[3] = (jt == 3u) ? sel : 0u;
  return r.s;
}

// Build W_cat[o][k]: k<1024 -> bf16(base_weight[o][k]); else bf16(coeff[o][k-1024])
__global__ __launch_bounds__(256) void build_w_kernel(
    const float* __restrict__ bw, const float* __restrict__ coeff,
    unsigned short* __restrict__ wc) {
  int id = blockIdx.x * 256 + threadIdx.x;
  int row = id / (KTOT / 8);
  int k8 = id - row * (KTOT / 8);
  int k = k8 * 8;
  const float* src = (k < INF) ? (bw + (size_t)row * INF + k)
                               : (coeff + (size_t)row * (INF * GRID_G) + (k - INF));
  const float4* s4 = (const float4*)src;
  float4 a = s4[0], b = s4[1];
  u16x8_t v;
  v[0] = f2bf(a.x); v[1] = f2bf(a.y); v[2] = f2bf(a.z); v[3] = f2bf(a.w);
  v[4] = f2bf(b.x); v[5] = f2bf(b.y); v[6] = f2bf(b.z); v[7] = f2bf(b.w);
  *(u16x8_t*)(wc + (size_t)id * 8) = v;
}

// Per (b,i): Xbf = bf16(x); Apack = bf16(0.1*w) | (idx<<16)
__global__ __launch_bounds__(256) void build_apack_kernel(
    const float* __restrict__ x, const float* __restrict__ grid,
    unsigned short* __restrict__ xbf, unsigned int* __restrict__ ap) {
  __shared__ float sg[GRID_G + 1];
  if (threadIdx.x <= GRID_G) sg[threadIdx.x] = grid[threadIdx.x];
  __syncthreads();
  int id = blockIdx.x * 256 + threadIdx.x;
  float xv = x[id];
  xbf[id] = f2bf(xv);
  float xc = fminf(fmaxf(xv, -1.0f), 1.0f);
  int cnt = 0;
#pragma unroll
  for (int j = 0; j <= GRID_G; ++j) cnt += (xc >= sg[j]) ? 1 : 0;
  int idx = cnt - 1;
  idx = idx < 0 ? 0 : (idx > GRID_G - 1 ? GRID_G - 1 : idx);
  float left = sg[idx], right = sg[idx + 1];
  float denom = right - left;
  denom = (denom == 0.0f) ? 1.0f : denom;
  float w = (xc - left) / denom;
  ap[id] = (unsigned int)f2bf(0.1f * w) | ((unsigned int)idx << 16);
}

// Fused 256x256 split-K GEMM (R11's kernel, best in-graph core ~880 TF) with
// SPLIT-K FIXUP epilogue replacing the separate reduce kernel:
//   - bid decode sk-major: partners of tile t0 share bid%8 (same-XCD heuristic
//     for Part L2 locality; correctness does NOT depend on placement).
//   - each block: write bf16 Part slab -> __threadfence (device release) ->
//     atomicAdd(cnt[tile]); the 8th arriver re-reads all 8 slabs in FIXED
//     order (deterministic f32 sum) and writes d_out. No waits -> no deadlock.
__global__ __launch_bounds__(512, 2) void fused_gemm_kernel(
    const unsigned short* __restrict__ Xb, const unsigned int* __restrict__ Ap,
    const unsigned short* __restrict__ Wc, unsigned short* __restrict__ P,
    int* __restrict__ tc, float* __restrict__ out) {
  __shared__ unsigned short LA[2][2][256 * 32];  // 64 KB
  __shared__ unsigned short LB[2][2][256 * 32];  // 64 KB

  int bid = blockIdx.x;
  int sk = bid >> 5;         // sk-major: partners (same tile) are 32 apart
  int t0i = bid & 31;        // 0..31
  int mt = t0i >> 2, nt = t0i & 3;

  int tid = threadIdx.x, wave = tid >> 6, lane = tid & 63;
  int wr = wave >> 2, wc = wave & 3;   // 2x4 wave grid; per-wave C = 128x64
  int lr = lane & 15, lk = lane >> 4;
  int rlo = lk * 128 + lr * 8;         // chunk-transposed read offset

  // dense staging source (chunk-transpose): lane -> row wave*16+(l&15), chunk l>>4
  int srow = wave * 16 + (lane & 15);
  int scol = ((lane >> 4) & 3) * 8;
  const unsigned short* gXA  = Xb + (size_t)(mt * 256 + srow) * INF + sk * 128 + scol;
  const unsigned short* gXA2 = gXA + (size_t)128 * INF;
  const unsigned short* gB   = Wc + (size_t)(nt * 256 + srow) * KTOT + scol;
  const unsigned short* gB2  = gB + (size_t)128 * KTOT;
  // packed-A source: lane l -> row wave*32+(l>>1), 4 u32 at iword (l&1)*4
  const unsigned int* gAP = Ap + (size_t)(mt * 256 + wave * 32 + (lane >> 1)) * INF
                            + sk * 128 + (lane & 1) * 4;

  unsigned int* APK0 = (unsigned int*)&LA[0][0][0];
  unsigned int* APK1 = (unsigned int*)&LA[1][0][0];

  const int CB = sk * 128;           // base col range base
  const int CS = 1024 + sk * 1024;   // spline col range base

  f32x4_t acc[2][4][4];
#pragma unroll
  for (int ch = 0; ch < 2; ++ch)
#pragma unroll
    for (int mf = 0; mf < 4; ++mf)
#pragma unroll
      for (int nf = 0; nf < 4; ++nf) acc[ch][mf][nf] = f32x4_t{0.f, 0.f, 0.f, 0.f};

#define VMW(N) asm volatile("s_waitcnt vmcnt(" #N ")" ::: "memory")
#define BARR() { __builtin_amdgcn_s_barrier(); asm volatile("" ::: "memory"); }
#define STAGE_XA(nb, ks, colofs) { unsigned short* d_ = &LA[nb][ks][wave * 512]; \
    async16(d_, gXA + (colofs) + (ks) * 32); \
    async16(d_ + 4096, gXA2 + (colofs) + (ks) * 32); }
#define STAGE_B(nb, ks, colofs) { unsigned short* d_ = &LB[nb][ks][wave * 512]; \
    async16(d_, gB + (colofs) + (ks) * 32); \
    async16(d_ + 4096, gB2 + (colofs) + (ks) * 32); }
#define STAGE_APK(APKn, tt) { async16((void*)((APKn) + wave * 256), gAP + ((tt) - 2) * 8); }
#define DSR_A(af_, CC, ks, ch) { _Pragma("unroll") for (int mf = 0; mf < 4; ++mf) \
    af_[mf] = *(const short8_t*)&LA[CC][ks][(wr * 8 + (ch) * 4 + mf) * 512 + rlo]; }
#define DSR_B(bf_, CC, ks) { _Pragma("unroll") for (int nf = 0; nf < 4; ++nf) \
    bf_[nf] = *(const short8_t*)&LB[CC][ks][(wc * 4 + nf) * 512 + rlo]; }
#define PRD(pr_, APKc, ks, ch) { _Pragma("unroll") for (int mf = 0; mf < 4; ++mf) \
    pr_[mf] = (APKc)[(wr * 128 + (ch) * 64 + mf * 16 + lr) * 8 + (ks) * 4 + lk]; }
#define EXPAND(af_, pr_) { _Pragma("unroll") for (int mf = 0; mf < 4; ++mf) \
    af_[mf] = onehot_frag(pr_[mf]); }
#define MFMA16(CH, af_, bf_) { __builtin_amdgcn_s_setprio(1); \
    _Pragma("unroll") for (int mf = 0; mf < 4; ++mf) \
    _Pragma("unroll") for (int nf = 0; nf < 4; ++nf) \
      acc[CH][mf][nf] = __builtin_amdgcn_mfma_f32_16x16x32_bf16( \
          af_[mf], bf_[nf], acc[CH][mf][nf], 0, 0, 0); \
    __builtin_amdgcn_s_setprio(0); }

  // prologue: tile0 (base) into buf0; order A0,B0,A1,B1
  STAGE_XA(0, 0, 0) STAGE_B(0, 0, CB) STAGE_XA(0, 1, 0) STAGE_B(0, 1, CB)

  { // tile0: base, c=0; stages t1(base)->buf1
    short8_t af[4], bf[4];
    VMW(4); BARR();
    DSR_A(af, 0, 0, 0) DSR_B(bf, 0, 0)
    STAGE_XA(1, 0, 64)
    MFMA16(0, af, bf)
    DSR_A(af, 0, 0, 1)
    STAGE_B(1, 0, CB + 64)
    MFMA16(1, af, bf)
    VMW(4); BARR();
    DSR_A(af, 0, 1, 0) DSR_B(bf, 0, 1)
    STAGE_XA(1, 1, 64)
    MFMA16(0, af, bf)
    DSR_A(af, 0, 1, 1)
    STAGE_B(1, 1, CB + 64)
    MFMA16(1, af, bf)
  }
  { // tile1: base, c=1; stages t2(spline)->buf0: APK@ph0, B0@ph1, B1@ph2
    short8_t af[4], bf[4];
    VMW(4); BARR();
    DSR_A(af, 1, 0, 0) DSR_B(bf, 1, 0)
    STAGE_APK(APK0, 2)
    MFMA16(0, af, bf)
    DSR_A(af, 1, 0, 1)
    STAGE_B(0, 0, CS)
    MFMA16(1, af, bf)
    VMW(3); BARR();
    DSR_A(af, 1, 1, 0) DSR_B(bf, 1, 1)
    STAGE_B(0, 1, CS)
    MFMA16(0, af, bf)
    DSR_A(af, 1, 1, 1)
    MFMA16(1, af, bf)
  }
  // spline tiles t=2..17
  for (int t = 2; t < 18; ++t) {
    int c = t & 1;
    unsigned int* APKc = c ? APK1 : APK0;
    unsigned int* APKn = c ? APK0 : APK1;
    int nb = c ^ 1;
    bool pf = t < 17;
    int cs = CS + (t - 1) * 64;   // (t+1-2)*64
    short8_t af[4], bf[4];
    unsigned int pr[4];
    VMW(2); BARR();
    PRD(pr, APKc, 0, 0) DSR_B(bf, c, 0)
    if (pf) STAGE_APK(APKn, t + 1)
    EXPAND(af, pr) MFMA16(0, af, bf)
    PRD(pr, APKc, 0, 1)
    if (pf) STAGE_B(nb, 0, cs)
    EXPAND(af, pr) MFMA16(1, af, bf)
    if (pf) { VMW(3); } else { VMW(0); }
    BARR();
    PRD(pr, APKc, 1, 0) DSR_B(bf, c, 1)
    if (pf) STAGE_B(nb, 1, cs)
    EXPAND(af, pr) MFMA16(0, af, bf)
    PRD(pr, APKc, 1, 1)
    EXPAND(af, pr) MFMA16(1, af, bf)
  }

  // partial-slab write: C/D col=lane&15 (n), row=(lane>>4)*4+reg (m)
  unsigned short* slab = P + (size_t)sk * CSLAB;
#pragma unroll
  for (int ch = 0; ch < 2; ++ch)
#pragma unroll
    for (int mf = 0; mf < 4; ++mf)
#pragma unroll
      for (int nf = 0; nf < 4; ++nf) {
        int col = nt * 256 + wc * 64 + nf * 16 + lr;
        int rowb = mt * 256 + wr * 128 + ch * 64 + mf * 16 + lk * 4;
#pragma unroll
        for (int r = 0; r < 4; ++r)
          slab[(size_t)(rowb + r) * OUTF + col] = f2bf(acc[ch][mf][nf][r]);
      }

  // split-K fixup: last arriver per tile reduces all 8 slabs -> f32 d_out.
  __threadfence();                       // release: slab writes visible device-wide
  __shared__ int lastflag;
  if (tid == 0) lastflag = (atomicAdd(&tc[t0i], 1) == SK - 1) ? 1 : 0;
  __syncthreads();
  if (lastflag) {
    __threadfence();                     // acquire: see partners' slab writes
#pragma unroll 1
    for (int cch = 0; cch < 16; ++cch) {
      int rl = cch * 16 + (tid >> 5);          // 16 rows per pass
      int cl = (tid & 31) * 8;                 // 8 cols per thread, coalesced
      size_t base = (size_t)(mt * 256 + rl) * OUTF + nt * 256 + cl;
      float s8[8];
#pragma unroll
      for (int j = 0; j < 8; ++j) s8[j] = 0.0f;
#pragma unroll
      for (int s = 0; s < SK; ++s) {
        u16x8_t v = *(const u16x8_t*)(P + (size_t)s * CSLAB + base);
#pragma unroll
        for (int j = 0; j < 8; ++j) s8[j] += bf2f(v[j]);
      }
      float4 lo = {s8[0], s8[1], s8[2], s8[3]};
      float4 hi = {s8[4], s8[5], s8[6], s8[7]};
      *(float4*)(out + base) = lo;
      *(float4*)(out + base + 4) = hi;
    }
  }
}

extern "C" void kernel_launch(void* const* d_in, const int* in_sizes, int n_in,
                              void* d_out, int out_size, void* d_ws, size_t ws_size,
                              hipStream_t stream) {
  const float* x = (const float*)d_in[0];
  const float* bw = (const float*)d_in[1];
  const float* coeff = (const float*)d_in[2];
  const float* grid = (const float*)d_in[3];
  float* out = (float*)d_out;

  unsigned short* Wcat = (unsigned short*)d_ws;                        // 18.87 MB
  unsigned short* Xbf  = Wcat + (size_t)OUTF * KTOT;                   //  4.19 MB
  unsigned int*   Apack = (unsigned int*)(Xbf + (size_t)BATCH * INF);  //  8.39 MB
  unsigned short* Part = (unsigned short*)(Apack + (size_t)BATCH * INF); // 8 x 4.19 MB
  int* tcnt = (int*)(Part + (size_t)SK * CSLAB);                       // 32 ints

  hipMemsetAsync(tcnt, 0, 32 * sizeof(int), stream);
  build_w_kernel<<<OUTF * (KTOT / 8) / 256, 256, 0, stream>>>(bw, coeff, Wcat);
  build_apack_kernel<<<BATCH * INF / 256, 256, 0, stream>>>(x, grid, Xbf, Apack);
  fused_gemm_kernel<<<SK * MTT * NTT, 512, 0, stream>>>(Xbf, Apack, Wcat, Part, tcnt, out);
}

// Round 15
// 68.259 us; speedup vs baseline: 2.4211x; 2.4211x over previous
//
#include <hip/hip_runtime.h>
#include <stdint.h>

#define BATCH 2048
#define INF 1024
#define OUTF 1024
#define GRID_G 8
#define KTOT 9216   // INF + INF*GRID_G (Wcat layout)

#define SK 8
#define MTT 8            // BATCH/256
#define NTT 4            // OUTF/256
#define CSLAB ((size_t)BATCH * OUTF)

#define WITEMS (OUTF * (KTOT / 8))        // 1179648 build_w items (8 elem each)
#define WBLK (WITEMS / 256)               // 4608 blocks
#define ABLK ((BATCH * INF / 4) / 256)    // 2048 blocks (4 elem/thread)

typedef __attribute__((ext_vector_type(8))) short short8_t;
typedef __attribute__((ext_vector_type(4))) float f32x4_t;
typedef __attribute__((ext_vector_type(8))) unsigned short u16x8_t;

__device__ __forceinline__ unsigned short f2bf(float f) {
  unsigned int u = __float_as_uint(f);
  u += 0x7FFFu + ((u >> 16) & 1u);
  return (unsigned short)(u >> 16);
}

__device__ __forceinline__ float bf2f(unsigned short h) {
  return __uint_as_float((unsigned int)h << 16);
}

__device__ __forceinline__ void async16(void* lds, const void* g) {
  __builtin_amdgcn_global_load_lds(
      (const __attribute__((address_space(1))) void*)g,
      (__attribute__((address_space(3))) void*)lds, 16, 0, 0);
}

// frag[j] = (j==idx) ? w : 0 over 8 bf16, from packed (bf16 w | idx<<16)
__device__ __forceinline__ short8_t onehot_frag(unsigned int p) {
  unsigned int wlo = p & 0xFFFFu;
  unsigned int idx = p >> 16;
  unsigned int sel = (idx & 1u) ? (wlo << 16) : wlo;
  unsigned int jt = idx >> 1;
  union { unsigned int u[4]; short8_t s; } r;
  r.u[0] = (jt == 0u) ? sel : 0u;
  r.u[1] = (jt == 1u) ? sel : 0u;
  r.u[2] = (jt == 2u) ? sel : 0u;
  r.u[3] = (jt == 3u) ? sel : 0u;
  return r.s;
}

// Merged prep: blocks [0,WBLK) build Wcat (8 elem/thread); blocks [WBLK,
// WBLK+ABLK) build Xbf + Apack (4 elem/thread, float4-vectorized).
__global__ __launch_bounds__(256) void build_all_kernel(
    const float* __restrict__ bw, const float* __restrict__ coeff,
    const float* __restrict__ x, const float* __restrict__ grid,
    unsigned short* __restrict__ wc, unsigned short* __restrict__ xbf,
    unsigned int* __restrict__ ap) {
  int blk = blockIdx.x;
  if (blk < WBLK) {
    int id = blk * 256 + threadIdx.x;
    int row = id / (KTOT / 8);
    int k8 = id - row * (KTOT / 8);
    int k = k8 * 8;
    const float* src = (k < INF) ? (bw + (size_t)row * INF + k)
                                 : (coeff + (size_t)row * (INF * GRID_G) + (k - INF));
    const float4* s4 = (const float4*)src;
    float4 a = s4[0], b = s4[1];
    u16x8_t v;
    v[0] = f2bf(a.x); v[1] = f2bf(a.y); v[2] = f2bf(a.z); v[3] = f2bf(a.w);
    v[4] = f2bf(b.x); v[5] = f2bf(b.y); v[6] = f2bf(b.z); v[7] = f2bf(b.w);
    *(u16x8_t*)(wc + (size_t)id * 8) = v;
  } else {
    __shared__ float sg[GRID_G + 1];
    if (threadIdx.x <= GRID_G) sg[threadIdx.x] = grid[threadIdx.x];
    __syncthreads();
    int id4 = (blk - WBLK) * 256 + threadIdx.x;   // one per 4 elements
    float4 xv4 = *(const float4*)(x + (size_t)id4 * 4);
    float xs[4] = {xv4.x, xv4.y, xv4.z, xv4.w};
    unsigned short xb[4];
    unsigned int ph[4];
#pragma unroll
    for (int e = 0; e < 4; ++e) {
      float xv = xs[e];
      xb[e] = f2bf(xv);
      float xc = fminf(fmaxf(xv, -1.0f), 1.0f);
      int cnt = 0;
#pragma unroll
      for (int j = 0; j <= GRID_G; ++j) cnt += (xc >= sg[j]) ? 1 : 0;
      int idx = cnt - 1;
      idx = idx < 0 ? 0 : (idx > GRID_G - 1 ? GRID_G - 1 : idx);
      float left = sg[idx], right = sg[idx + 1];
      float denom = right - left;
      denom = (denom == 0.0f) ? 1.0f : denom;
      float w = (xc - left) / denom;
      ph[e] = (unsigned int)f2bf(0.1f * w) | ((unsigned int)idx << 16);
    }
    *(ushort2*)(xbf + (size_t)id4 * 4) = ushort2{xb[0], xb[1]};
    *(ushort2*)(xbf + (size_t)id4 * 4 + 2) = ushort2{xb[2], xb[3]};
    uint4 pv = {ph[0], ph[1], ph[2], ph[3]};
    *(uint4*)(ap + (size_t)id4 * 4) = pv;
  }
}

// Fused 256x256 split-K GEMM — R11's kernel verbatim (best measured core).
// 2 dense base tiles (Xbf) + 16 spline tiles (packed-A, in-reg one-hot).
// sk = bid&7: XCD<->slab affinity (each XCD touches only its 7 MB slice).
__global__ __launch_bounds__(512, 2) void fused_gemm_kernel(
    const unsigned short* __restrict__ Xb, const unsigned int* __restrict__ Ap,
    const unsigned short* __restrict__ Wc, unsigned short* __restrict__ P) {
  __shared__ unsigned short LA[2][2][256 * 32];  // 64 KB
  __shared__ unsigned short LB[2][2][256 * 32];  // 64 KB

  int bid = blockIdx.x;
  int sk = bid & 7;          // XCD affinity
  int t0i = bid >> 3;        // 0..31
  int mt = t0i >> 2, nt = t0i & 3;

  int tid = threadIdx.x, wave = tid >> 6, lane = tid & 63;
  int wr = wave >> 2, wc = wave & 3;   // 2x4 wave grid; per-wave C = 128x64
  int lr = lane & 15, lk = lane >> 4;
  int rlo = lk * 128 + lr * 8;         // chunk-transposed read offset

  int srow = wave * 16 + (lane & 15);
  int scol = ((lane >> 4) & 3) * 8;
  const unsigned short* gXA  = Xb + (size_t)(mt * 256 + srow) * INF + sk * 128 + scol;
  const unsigned short* gXA2 = gXA + (size_t)128 * INF;
  const unsigned short* gB   = Wc + (size_t)(nt * 256 + srow) * KTOT + scol;
  const unsigned short* gB2  = gB + (size_t)128 * KTOT;
  const unsigned int* gAP = Ap + (size_t)(mt * 256 + wave * 32 + (lane >> 1)) * INF
                            + sk * 128 + (lane & 1) * 4;

  unsigned int* APK0 = (unsigned int*)&LA[0][0][0];
  unsigned int* APK1 = (unsigned int*)&LA[1][0][0];

  const int CB = sk * 128;           // base col range base
  const int CS = 1024 + sk * 1024;   // spline col range base

  f32x4_t acc[2][4][4];
#pragma unroll
  for (int ch = 0; ch < 2; ++ch)
#pragma unroll
    for (int mf = 0; mf < 4; ++mf)
#pragma unroll
      for (int nf = 0; nf < 4; ++nf) acc[ch][mf][nf] = f32x4_t{0.f, 0.f, 0.f, 0.f};

#define VMW(N) asm volatile("s_waitcnt vmcnt(" #N ")" ::: "memory")
#define BARR() { __builtin_amdgcn_s_barrier(); asm volatile("" ::: "memory"); }
#define STAGE_XA(nb, ks, colofs) { unsigned short* d_ = &LA[nb][ks][wave * 512]; \
    async16(d_, gXA + (colofs) + (ks) * 32); \
    async16(d_ + 4096, gXA2 + (colofs) + (ks) * 32); }
#define STAGE_B(nb, ks, colofs) { unsigned short* d_ = &LB[nb][ks][wave * 512]; \
    async16(d_, gB + (colofs) + (ks) * 32); \
    async16(d_ + 4096, gB2 + (colofs) + (ks) * 32); }
#define STAGE_APK(APKn, tt) { async16((void*)((APKn) + wave * 256), gAP + ((tt) - 2) * 8); }
#define DSR_A(af_, CC, ks, ch) { _Pragma("unroll") for (int mf = 0; mf < 4; ++mf) \
    af_[mf] = *(const short8_t*)&LA[CC][ks][(wr * 8 + (ch) * 4 + mf) * 512 + rlo]; }
#define DSR_B(bf_, CC, ks) { _Pragma("unroll") for (int nf = 0; nf < 4; ++nf) \
    bf_[nf] = *(const short8_t*)&LB[CC][ks][(wc * 4 + nf) * 512 + rlo]; }
#define PRD(pr_, APKc, ks, ch) { _Pragma("unroll") for (int mf = 0; mf < 4; ++mf) \
    pr_[mf] = (APKc)[(wr * 128 + (ch) * 64 + mf * 16 + lr) * 8 + (ks) * 4 + lk]; }
#define EXPAND(af_, pr_) { _Pragma("unroll") for (int mf = 0; mf < 4; ++mf) \
    af_[mf] = onehot_frag(pr_[mf]); }
#define MFMA16(CH, af_, bf_) { __builtin_amdgcn_s_setprio(1); \
    _Pragma("unroll") for (int mf = 0; mf < 4; ++mf) \
    _Pragma("unroll") for (int nf = 0; nf < 4; ++nf) \
      acc[CH][mf][nf] = __builtin_amdgcn_mfma_f32_16x16x32_bf16( \
          af_[mf], bf_[nf], acc[CH][mf][nf], 0, 0, 0); \
    __builtin_amdgcn_s_setprio(0); }

  // prologue: tile0 (base) into buf0; order A0,B0,A1,B1
  STAGE_XA(0, 0, 0) STAGE_B(0, 0, CB) STAGE_XA(0, 1, 0) STAGE_B(0, 1, CB)

  { // tile0: base, c=0; stages t1(base)->buf1
    short8_t af[4], bf[4];
    VMW(4); BARR();
    DSR_A(af, 0, 0, 0) DSR_B(bf, 0, 0)
    STAGE_XA(1, 0, 64)
    MFMA16(0, af, bf)
    DSR_A(af, 0, 0, 1)
    STAGE_B(1, 0, CB + 64)
    MFMA16(1, af, bf)
    VMW(4); BARR();
    DSR_A(af, 0, 1, 0) DSR_B(bf, 0, 1)
    STAGE_XA(1, 1, 64)
    MFMA16(0, af, bf)
    DSR_A(af, 0, 1, 1)
    STAGE_B(1, 1, CB + 64)
    MFMA16(1, af, bf)
  }
  { // tile1: base, c=1; stages t2(spline)->buf0: APK@ph0, B0@ph1, B1@ph2
    short8_t af[4], bf[4];
    VMW(4); BARR();
    DSR_A(af, 1, 0, 0) DSR_B(bf, 1, 0)
    STAGE_APK(APK0, 2)
    MFMA16(0, af, bf)
    DSR_A(af, 1, 0, 1)
    STAGE_B(0, 0, CS)
    MFMA16(1, af, bf)
    VMW(3); BARR();
    DSR_A(af, 1, 1, 0) DSR_B(bf, 1, 1)
    STAGE_B(0, 1, CS)
    MFMA16(0, af, bf)
    DSR_A(af, 1, 1, 1)
    MFMA16(1, af, bf)
  }
  // spline tiles t=2..17
  for (int t = 2; t < 18; ++t) {
    int c = t & 1;
    unsigned int* APKc = c ? APK1 : APK0;
    unsigned int* APKn = c ? APK0 : APK1;
    int nb = c ^ 1;
    bool pf = t < 17;
    int cs = CS + (t - 1) * 64;   // (t+1-2)*64
    short8_t af[4], bf[4];
    unsigned int pr[4];
    VMW(2); BARR();
    PRD(pr, APKc, 0, 0) DSR_B(bf, c, 0)
    if (pf) STAGE_APK(APKn, t + 1)
    EXPAND(af, pr) MFMA16(0, af, bf)
    PRD(pr, APKc, 0, 1)
    if (pf) STAGE_B(nb, 0, cs)
    EXPAND(af, pr) MFMA16(1, af, bf)
    if (pf) { VMW(3); } else { VMW(0); }
    BARR();
    PRD(pr, APKc, 1, 0) DSR_B(bf, c, 1)
    if (pf) STAGE_B(nb, 1, cs)
    EXPAND(af, pr) MFMA16(0, af, bf)
    PRD(pr, APKc, 1, 1)
    EXPAND(af, pr) MFMA16(1, af, bf)
  }

  // epilogue: C/D col=lane&15 (n), row=(lane>>4)*4+reg (m); private bf16 slab
  unsigned short* slab = P + (size_t)sk * CSLAB;
#pragma unroll
  for (int ch = 0; ch < 2; ++ch)
#pragma unroll
    for (int mf = 0; mf < 4; ++mf)
#pragma unroll
      for (int nf = 0; nf < 4; ++nf) {
        int col = nt * 256 + wc * 64 + nf * 16 + lr;
        int rowb = mt * 256 + wr * 128 + ch * 64 + mf * 16 + lk * 4;
#pragma unroll
        for (int r = 0; r < 4; ++r)
          slab[(size_t)(rowb + r) * OUTF + col] = f2bf(acc[ch][mf][nf][r]);
      }
}

// out[e] = sum over 8 partial slabs; 8 elements/thread, overwrites d_out.
__global__ __launch_bounds__(256) void reduce_kernel(
    const unsigned short* __restrict__ P, float* __restrict__ out) {
  size_t base = ((size_t)blockIdx.x * 256 + threadIdx.x) * 8;
  float s[8];
#pragma unroll
  for (int j = 0; j < 8; ++j) s[j] = 0.0f;
#pragma unroll
  for (int k = 0; k < SK; ++k) {
    u16x8_t v = *(const u16x8_t*)(P + (size_t)k * CSLAB + base);
#pragma unroll
    for (int j = 0; j < 8; ++j)
      s[j] += bf2f(v[j]);
  }
  float4 lo = {s[0], s[1], s[2], s[3]};
  float4 hi = {s[4], s[5], s[6], s[7]};
  *(float4*)(out + base) = lo;
  *(float4*)(out + base + 4) = hi;
}

extern "C" void kernel_launch(void* const* d_in, const int* in_sizes, int n_in,
                              void* d_out, int out_size, void* d_ws, size_t ws_size,
                              hipStream_t stream) {
  const float* x = (const float*)d_in[0];
  const float* bw = (const float*)d_in[1];
  const float* coeff = (const float*)d_in[2];
  const float* grid = (const float*)d_in[3];
  float* out = (float*)d_out;

  unsigned short* Wcat = (unsigned short*)d_ws;                        // 18.87 MB
  unsigned short* Xbf  = Wcat + (size_t)OUTF * KTOT;                   //  4.19 MB
  unsigned int*   Apack = (unsigned int*)(Xbf + (size_t)BATCH * INF);  //  8.39 MB
  unsigned short* Part = (unsigned short*)(Apack + (size_t)BATCH * INF); // 8 x 4.19 MB

  build_all_kernel<<<WBLK + ABLK, 256, 0, stream>>>(bw, coeff, x, grid, Wcat, Xbf, Apack);
  fused_gemm_kernel<<<SK * MTT * NTT, 512, 0, stream>>>(Xbf, Apack, Wcat, Part);
  reduce_kernel<<<(int)(CSLAB / 8 / 256), 256, 0, stream>>>(Part, out);
}